// Round 8
// baseline (722.641 us; speedup 1.0000x reference)
//
#include <hip/hip_runtime.h>
#include <hip/hip_cooperative_groups.h>
#include <math.h>

namespace cg = cooperative_groups;

// ---------------------------------------------------------------------------
// GNNEncoder as ONE persistent cooperative kernel (256 blocks x 256 thr).
// Phases (grid.sync between): bucket-hist -> colscan -> edge scatter ->
// kB1(deg/dis/offs) -> kB2(col2) -> [gemm -> agg] x3 -> pool+MLP head.
// H bf16 two channel-half slabs; gemms on MFMA 16x16x32 bf16; aggs gather
// one 64B line per edge per half; pool via wave shuffles (no barriers).
// ---------------------------------------------------------------------------

typedef short short8 __attribute__((ext_vector_type(8)));
typedef float f32x4 __attribute__((ext_vector_type(4)));

__device__ inline float bf2f(unsigned short h) {
    return __uint_as_float((unsigned)h << 16);
}
__device__ inline float4 bh4f(ushort4 u) {
    return make_float4(bf2f(u.x), bf2f(u.y), bf2f(u.z), bf2f(u.w));
}
__device__ inline unsigned short f2bf(float f) {  // round-to-nearest-even
    unsigned u = __float_as_uint(f);
    return (unsigned short)((u + (0x7FFFu + ((u >> 16) & 1u))) >> 16);
}
__device__ inline float4 f4fma(float s, float4 a, float4 acc) {
    acc.x += s * a.x; acc.y += s * a.y; acc.z += s * a.z; acc.w += s * a.w;
    return acc;
}

struct MegaP {
    const float* x; const int* ei; const int* bat;
    const float* W1; const float* b1; const float* W2; const float* b2;
    const float* W3; const float* b3;
    const float* Wp1; const float* bp1; const float* Wp2; const float* bp2;
    int* hist; int* cursorA; int* tot; unsigned* ebuf;
    int* offs; float2* col2; float* dis;
    unsigned short* Hb; float* X1; float* X2; float* S;
    float* out;
    int N, E, G, NBUK;
};

// dense transform phase: D[ch][node] = sum_k W[k][ch]*X[node][k], bf16 slabs
template <int K>
__device__ inline void gemm_phase(const float* __restrict__ X, const float* __restrict__ W,
                                  unsigned short* __restrict__ H, int n, short* wt) {
    int t = threadIdx.x;
    for (int idx = t; idx < 64 * K; idx += 256) {
        int k = idx >> 6, ch = idx & 63;
        wt[ch * K + k] = (short)f2bf(W[idx]);
    }
    __syncthreads();
    int wave = t >> 6, lane = t & 63;
    int q = lane >> 4, l = lane & 15;
    short8 afr[4][K / 32];
#pragma unroll
    for (int mb = 0; mb < 4; mb++)
#pragma unroll
        for (int s = 0; s < K / 32; s++)
            afr[mb][s] = *(const short8*)(wt + (mb * 16 + l) * K + s * 32 + q * 8);
    int ntiles = n >> 4;  // N % 16 == 0
    int stride = gridDim.x * 4;
    for (int tile = blockIdx.x * 4 + wave; tile < ntiles; tile += stride) {
        int node = tile * 16 + l;
        f32x4 acc[4] = {};
        const float* xr = X + (size_t)node * K + q * 8;
#pragma unroll
        for (int s = 0; s < K / 32; s++) {
            float4 xa = *(const float4*)(xr + s * 32);
            float4 xb = *(const float4*)(xr + s * 32 + 4);
            short8 bfr;
            bfr[0] = (short)f2bf(xa.x); bfr[1] = (short)f2bf(xa.y);
            bfr[2] = (short)f2bf(xa.z); bfr[3] = (short)f2bf(xa.w);
            bfr[4] = (short)f2bf(xb.x); bfr[5] = (short)f2bf(xb.y);
            bfr[6] = (short)f2bf(xb.z); bfr[7] = (short)f2bf(xb.w);
#pragma unroll
            for (int mb = 0; mb < 4; mb++)
                acc[mb] = __builtin_amdgcn_mfma_f32_16x16x32_bf16(afr[mb][s], bfr, acc[mb], 0, 0, 0);
        }
#pragma unroll
        for (int mb = 0; mb < 4; mb++) {
            ushort4 u;
            u.x = f2bf(acc[mb][0]); u.y = f2bf(acc[mb][1]);
            u.z = f2bf(acc[mb][2]); u.w = f2bf(acc[mb][3]);
            ushort4* slab = (ushort4*)H + (size_t)(mb >> 1) * (size_t)n * 8;
            slab[(size_t)node * 8 + (mb & 1) * 4 + q] = u;
        }
    }
    __syncthreads();
}

// aggregation phase: half-split slabs, 8 lanes x ushort4 per node, 8x unroll
__device__ inline void agg_phase(const unsigned short* __restrict__ H,
                                 const float2* __restrict__ col2,
                                 const int* __restrict__ offs, const float* __restrict__ dis,
                                 const float* __restrict__ bias,
                                 const float* __restrict__ add1, const float* __restrict__ add2,
                                 float* __restrict__ Out, int n) {
    int b = blockIdx.x, t = threadIdx.x;
    int h = (b & 7) >> 2;                  // channel half (XCD heuristic)
    int base = (b >> 3) * 4 + (b & 3);     // [0,128): 128 blocks per half
    int lane = t & 7;
    int tiles = (n + 31) / 32;
    const ushort4* H4 = (const ushort4*)H + (size_t)h * (size_t)n * 8;
    float4 bb = ((const float4*)bias)[h * 8 + lane];
    for (int w = base; w < tiles; w += 128) {
        int node = w * 32 + (t >> 3);
        if (node >= n) continue;
        float dn = dis[node];
        float4 acc = bh4f(H4[(size_t)node * 8 + lane]);
        acc.x *= dn; acc.y *= dn; acc.z *= dn; acc.w *= dn;
        int lo = offs[node], hi = offs[node + 1];
        int p = lo;
        for (; p + 8 <= hi; p += 8) {
            float2 e[8]; float4 hv[8];
#pragma unroll
            for (int u = 0; u < 8; u++) e[u] = col2[p + u];
#pragma unroll
            for (int u = 0; u < 8; u++)
                hv[u] = bh4f(H4[(size_t)__float_as_int(e[u].x) * 8 + lane]);
#pragma unroll
            for (int u = 0; u < 8; u++) acc = f4fma(e[u].y, hv[u], acc);
        }
        for (; p < hi; p++) {
            float2 e = col2[p];
            acc = f4fma(e.y, bh4f(H4[(size_t)__float_as_int(e.x) * 8 + lane]), acc);
        }
        float4 v;
        v.x = fmaxf(acc.x * dn + bb.x, 0.f);
        v.y = fmaxf(acc.y * dn + bb.y, 0.f);
        v.z = fmaxf(acc.z * dn + bb.z, 0.f);
        v.w = fmaxf(acc.w * dn + bb.w, 0.f);
        size_t oi = (size_t)node * 16 + h * 8 + lane;
        if (add1) {
            float4 a1 = ((const float4*)add1)[oi];
            float4 a2 = ((const float4*)add2)[oi];
            v.x += a1.x + a2.x; v.y += a1.y + a2.y; v.z += a1.z + a2.z; v.w += a1.w + a2.w;
        }
        ((float4*)Out)[oi] = v;
    }
}

__global__ __launch_bounds__(256, 1) void k_mega(MegaP P) {
    cg::grid_group grid = cg::this_grid();
    __shared__ __align__(16) char smemraw[16384];
    short* wt = (short*)smemraw;
    int* sH = (int*)smemraw;            // [256]
    int* sS = (int*)(smemraw + 1024);   // [256]
    int* sC = (int*)(smemraw + 2048);   // [256]

    int t = threadIdx.x, b = blockIdx.x;
    int B = gridDim.x;  // 256
    int E = P.E, N = P.N;
    const int* src = P.ei;
    const int* dst = P.ei + E;
    int chunk = (E + B - 1) / B;

    // ---- phase 1: coarse bucket hist of dst>>8 ----
    sH[t] = 0;
    __syncthreads();
    {
        int e0 = b * chunk, e1 = min(e0 + chunk, E);
        for (int e = e0 + t; e < e1; e += 256) atomicAdd(&sH[dst[e] >> 8], 1);
    }
    __syncthreads();
    P.hist[b * 256 + t] = sH[t];
    grid.sync();

    // ---- phase 2: column scan (block b scans bucket b over all chunks) ----
    {
        int v = P.hist[t * 256 + b];
        sS[t] = v;
        __syncthreads();
        for (int st = 1; st < 256; st <<= 1) {
            int u = sS[t];
            if (t >= st) u += sS[t - st];
            __syncthreads();
            sS[t] = u;
            __syncthreads();
        }
        P.cursorA[t * 256 + b] = sS[t] - v;
        if (t == 255) P.tot[b] = sS[255];
    }
    grid.sync();

    // ---- phase 3: scatter packed edges into bucket-contiguous ebuf ----
    {
        sS[t] = P.tot[t];
        __syncthreads();
        for (int st = 1; st < 256; st <<= 1) {
            int u = sS[t];
            if (t >= st) u += sS[t - st];
            __syncthreads();
            sS[t] = u;
            __syncthreads();
        }
        int bstart = (t == 0) ? 0 : sS[t - 1];
        sC[t] = P.cursorA[b * 256 + t] + bstart;
        __syncthreads();
        int e0 = b * chunk, e1 = min(e0 + chunk, E);
        for (int e = e0 + t; e < e1; e += 256) {
            int d = dst[e];
            int p = atomicAdd(&sC[d >> 8], 1);
            P.ebuf[p] = ((unsigned)(d & 255) << 24) | (unsigned)src[e];
        }
    }
    grid.sync();

    // ---- phase 4 (kB1): per-bucket exact degree -> dis, offs ----
    if (b < P.NBUK) {
        sS[t] = P.tot[t];
        __syncthreads();
        for (int st = 1; st < 256; st <<= 1) {
            int u = sS[t];
            if (t >= st) u += sS[t - st];
            __syncthreads();
            sS[t] = u;
            __syncthreads();
        }
        int lo = (b == 0) ? 0 : sS[b - 1];
        int hi = sS[b];
        sH[t] = 0;
        __syncthreads();
        for (int p = lo + t; p < hi; p += 256) atomicAdd(&sH[P.ebuf[p] >> 24], 1);
        __syncthreads();
        int c = sH[t];
        int node = b * 256 + t;
        if (node < N) P.dis[node] = rsqrtf((float)(c + 1));  // +1 self-loop
        sS[t] = c;
        __syncthreads();
        for (int st = 1; st < 256; st <<= 1) {
            int u = sS[t];
            if (t >= st) u += sS[t - st];
            __syncthreads();
            sS[t] = u;
            __syncthreads();
        }
        if (node < N) P.offs[node] = lo + sS[t] - c;
        if (node == N - 1) P.offs[N] = E;
    }
    grid.sync();

    // ---- phase 5 (kB2): scatter col2 = (src, dis[src]) ----
    if (b < P.NBUK) {
        sS[t] = P.tot[t];
        __syncthreads();
        for (int st = 1; st < 256; st <<= 1) {
            int u = sS[t];
            if (t >= st) u += sS[t - st];
            __syncthreads();
            sS[t] = u;
            __syncthreads();
        }
        int lo = (b == 0) ? 0 : sS[b - 1];
        int hi = sS[b];
        int node = b * 256 + t;
        sC[t] = (node < N) ? P.offs[node] : 0;
        __syncthreads();
        for (int p = lo + t; p < hi; p += 256) {
            unsigned e = P.ebuf[p];
            int srcI = (int)(e & 0x00FFFFFFu);
            int q = atomicAdd(&sC[e >> 24], 1);
            P.col2[q] = make_float2(__int_as_float(srcI), P.dis[srcI]);
        }
    }
    grid.sync();

    // ---- layers ----
    gemm_phase<128>(P.x, P.W1, P.Hb, N, wt);
    grid.sync();
    agg_phase(P.Hb, P.col2, P.offs, P.dis, P.b1, nullptr, nullptr, P.X1, N);
    grid.sync();
    gemm_phase<64>(P.X1, P.W2, P.Hb, N, wt);
    grid.sync();
    agg_phase(P.Hb, P.col2, P.offs, P.dis, P.b2, nullptr, nullptr, P.X2, N);
    grid.sync();
    gemm_phase<64>(P.X2, P.W3, P.Hb, N, wt);
    grid.sync();
    agg_phase(P.Hb, P.col2, P.offs, P.dis, P.b3, P.X1, P.X2, P.S, N);
    grid.sync();

    // ---- phase 12: global_mean_pool + MLP head (one wave per graph) ----
    {
        int wv = t >> 6, j = t & 63;
        int per = B * 4;
        int niter = (P.G + per - 1) / per;
        for (int it = 0; it < niter; it++) {
            int g = (b * 4 + wv) + it * per;
            if (g >= P.G) continue;  // uniform across the wave
            int a = 0, e = N;
            while (a < e) { int m = (a + e) >> 1; if (P.bat[m] < g) a = m + 1; else e = m; }
            int beg = a;
            e = N;
            while (a < e) { int m = (a + e) >> 1; if (P.bat[m] < g + 1) a = m + 1; else e = m; }
            int end = a;
            float sum = 0.f;
            for (int i = beg; i < end; i++) sum += P.S[(size_t)i * 64 + j];
            float cnt = (float)(end - beg);
            float p = sum / fmaxf(cnt, 1.f);
            float t1 = P.bp1[j];
#pragma unroll 8
            for (int k = 0; k < 64; k++) t1 += __shfl(p, k) * P.Wp1[k * 64 + j];
            t1 = fmaxf(t1, 0.f);
            int jj = j & 31;
            float o = P.bp2[jj];
#pragma unroll 8
            for (int k = 0; k < 64; k++) o += __shfl(t1, k) * P.Wp2[k * 32 + jj];
            if (j < 32) P.out[(size_t)g * 32 + j] = o;
        }
    }
}

extern "C" void kernel_launch(void* const* d_in, const int* in_sizes, int n_in,
                              void* d_out, int out_size, void* d_ws, size_t ws_size,
                              hipStream_t stream) {
    MegaP P;
    P.x   = (const float*)d_in[0];
    P.ei  = (const int*)d_in[1];
    P.bat = (const int*)d_in[2];
    P.W1  = (const float*)d_in[3];  P.b1  = (const float*)d_in[4];
    P.W2  = (const float*)d_in[5];  P.b2  = (const float*)d_in[6];
    P.W3  = (const float*)d_in[7];  P.b3  = (const float*)d_in[8];
    P.Wp1 = (const float*)d_in[9];  P.bp1 = (const float*)d_in[10];
    P.Wp2 = (const float*)d_in[11]; P.bp2 = (const float*)d_in[12];
    P.N = in_sizes[0] / 128;
    P.E = in_sizes[1] / 2;
    P.G = out_size / 32;
    P.NBUK = (P.N + 255) / 256;
    P.out = (float*)d_out;

    char* w = (char*)d_ws;
    auto alloc = [&](size_t bytes) -> void* {
        void* p = (void*)w;
        w += (bytes + 255) & ~(size_t)255;
        return p;
    };
    P.hist    = (int*)alloc((size_t)256 * 256 * 4);
    P.cursorA = (int*)alloc((size_t)256 * 256 * 4);
    P.tot     = (int*)alloc((size_t)256 * 4);
    P.ebuf    = (unsigned*)alloc((size_t)P.E * 4);
    P.offs    = (int*)alloc((size_t)(P.N + 1) * 4);
    P.col2    = (float2*)alloc((size_t)P.E * 8);
    P.dis     = (float*)alloc((size_t)P.N * 4);
    P.Hb      = (unsigned short*)alloc((size_t)P.N * 64 * 2);
    P.X1      = (float*)alloc((size_t)P.N * 64 * 4);
    P.X2      = (float*)alloc((size_t)P.N * 64 * 4);
    P.S       = (float*)alloc((size_t)P.N * 64 * 4);

    void* args[] = {&P};
    hipLaunchCooperativeKernel(reinterpret_cast<void*>(k_mega), dim3(256), dim3(256),
                               args, 0, stream);
}

// Round 9
// 245.034 us; speedup vs baseline: 2.9492x; 2.9492x over previous
//
#include <hip/hip_runtime.h>
#include <math.h>

// ---------------------------------------------------------------------------
// GNNEncoder: 3x GCNConv(relu) -> sum of layers -> global_mean_pool -> MLP
// Multi-kernel (max occupancy per phase; R8 mega-kernel experiment showed
// cooperative 1-block/CU kills latency hiding: 630us vs ~190us).
// CSR via bucketed counting sort, NO global atomics anywhere.
// H bf16 two channel-half slabs (Nx32, 3.2MB); X1/X2 bf16; S fp32.
// Gemms on MFMA 16x16x32 bf16. Aggs: 4 lanes x ushort8 (16B) per node-half
// -> one 64B line per edge per half, half-split XCD routing.
// ---------------------------------------------------------------------------

typedef short short8 __attribute__((ext_vector_type(8)));
typedef float f32x4 __attribute__((ext_vector_type(4)));

__device__ inline float bf2f(unsigned short h) {
    return __uint_as_float((unsigned)h << 16);
}
__device__ inline unsigned short f2bf(float f) {  // round-to-nearest-even
    unsigned u = __float_as_uint(f);
    return (unsigned short)((u + (0x7FFFu + ((u >> 16) & 1u))) >> 16);
}
__device__ inline void bh8f(short8 u, float4& a, float4& b) {
    a.x = bf2f((unsigned short)u[0]); a.y = bf2f((unsigned short)u[1]);
    a.z = bf2f((unsigned short)u[2]); a.w = bf2f((unsigned short)u[3]);
    b.x = bf2f((unsigned short)u[4]); b.y = bf2f((unsigned short)u[5]);
    b.z = bf2f((unsigned short)u[6]); b.w = bf2f((unsigned short)u[7]);
}
__device__ inline float4 f4fma(float s, float4 a, float4 acc) {
    acc.x += s * a.x; acc.y += s * a.y; acc.z += s * a.z; acc.w += s * a.w;
    return acc;
}

// ---- pass A: coarse bucket hist of dst>>8 (LDS only, no global atomics) ----
__global__ void kA_hist(const int* __restrict__ dst, int* __restrict__ hist,
                        int E, int chunk) {
    __shared__ int h[256];
    int t = threadIdx.x;
    h[t] = 0;
    __syncthreads();
    int e0 = blockIdx.x * chunk;
    int e1 = min(e0 + chunk, E);
    for (int e = e0 + t; e < e1; e += 256) atomicAdd(&h[dst[e] >> 8], 1);
    __syncthreads();
    hist[blockIdx.x * 256 + t] = h[t];
}

// block k scans column k of hist over chunk-blocks -> cursorA, tot
__global__ void kA_colscan(const int* __restrict__ hist, int* __restrict__ cursorA,
                           int* __restrict__ tot) {
    __shared__ int s[256];
    int t = threadIdx.x;
    int k = blockIdx.x;
    int v = hist[t * 256 + k];
    s[t] = v;
    __syncthreads();
    for (int st = 1; st < 256; st <<= 1) {
        int u = s[t];
        if (t >= st) u += s[t - st];
        __syncthreads();
        s[t] = u;
        __syncthreads();
    }
    cursorA[t * 256 + k] = s[t] - v;
    if (t == 255) tot[k] = s[255];
}

// scatter packed (dstLow<<24 | src) into bucket-contiguous ebuf
__global__ void kA_scatter(const int* __restrict__ src, const int* __restrict__ dst,
                           const int* __restrict__ cursorA, const int* __restrict__ tot,
                           unsigned* __restrict__ ebuf, int E, int chunk) {
    __shared__ int s[256];
    __shared__ int cur[256];
    int t = threadIdx.x;
    s[t] = tot[t];
    __syncthreads();
    for (int st = 1; st < 256; st <<= 1) {
        int u = s[t];
        if (t >= st) u += s[t - st];
        __syncthreads();
        s[t] = u;
        __syncthreads();
    }
    int bstart = (t == 0) ? 0 : s[t - 1];
    cur[t] = cursorA[blockIdx.x * 256 + t] + bstart;
    __syncthreads();
    int e0 = blockIdx.x * chunk;
    int e1 = min(e0 + chunk, E);
    for (int e = e0 + t; e < e1; e += 256) {
        int d = dst[e];
        int p = atomicAdd(&cur[d >> 8], 1);
        ebuf[p] = ((unsigned)(d & 255) << 24) | (unsigned)src[e];
    }
}

// kB1: per-bucket exact degree (LDS hist) -> dis, offs
__global__ void kB1(const unsigned* __restrict__ ebuf, const int* __restrict__ tot,
                    float* __restrict__ dis, int* __restrict__ offs, int N, int E) {
    __shared__ int s[256];
    __shared__ int h[256];
    int t = threadIdx.x;
    int k = blockIdx.x;
    s[t] = tot[t];
    __syncthreads();
    for (int st = 1; st < 256; st <<= 1) {
        int u = s[t];
        if (t >= st) u += s[t - st];
        __syncthreads();
        s[t] = u;
        __syncthreads();
    }
    int lo = (k == 0) ? 0 : s[k - 1];
    int hi = s[k];
    h[t] = 0;
    __syncthreads();
    for (int p = lo + t; p < hi; p += 256) atomicAdd(&h[ebuf[p] >> 24], 1);
    __syncthreads();
    int c = h[t];
    int node = k * 256 + t;
    if (node < N) dis[node] = rsqrtf((float)(c + 1));  // +1 self-loop
    s[t] = c;
    __syncthreads();
    for (int st = 1; st < 256; st <<= 1) {
        int u = s[t];
        if (t >= st) u += s[t - st];
        __syncthreads();
        s[t] = u;
        __syncthreads();
    }
    if (node < N) offs[node] = lo + s[t] - c;
    if (node == N - 1) offs[N] = E;
}

// kB2: scatter col2 = (src, dis[src]) into per-node CSR windows
__global__ void kB2(const unsigned* __restrict__ ebuf, const int* __restrict__ tot,
                    const float* __restrict__ dis, const int* __restrict__ offs,
                    float2* __restrict__ col2, int N, int E) {
    __shared__ int s[256];
    __shared__ int cur[256];
    int t = threadIdx.x;
    int k = blockIdx.x;
    s[t] = tot[t];
    __syncthreads();
    for (int st = 1; st < 256; st <<= 1) {
        int u = s[t];
        if (t >= st) u += s[t - st];
        __syncthreads();
        s[t] = u;
        __syncthreads();
    }
    int lo = (k == 0) ? 0 : s[k - 1];
    int hi = s[k];
    int node = k * 256 + t;
    cur[t] = (node < N) ? offs[node] : 0;
    __syncthreads();
    for (int p = lo + t; p < hi; p += 256) {
        unsigned e = ebuf[p];
        int srcI = (int)(e & 0x00FFFFFFu);
        int q = atomicAdd(&cur[e >> 24], 1);
        col2[q] = make_float2(__int_as_float(srcI), dis[srcI]);
    }
}

// ---- MFMA dense transforms: D[ch][node] = sum_k W[k][ch] * X[node][k] -----
// A = W^T bf16 (LDS), B = X^T bf16, C layout col=node,row=ch -> slab stores.

// fp32-input variant (layer 1, K=128)
template <int K>
__global__ __launch_bounds__(256) void k_gemm_f32(const float* __restrict__ X,
                                                  const float* __restrict__ W,
                                                  unsigned short* __restrict__ H, int n) {
    __shared__ short wt[64 * K];
    int t = threadIdx.x;
    for (int idx = t; idx < 64 * K; idx += 256) {
        int k = idx >> 6, ch = idx & 63;
        wt[ch * K + k] = (short)f2bf(W[idx]);
    }
    __syncthreads();
    int wave = t >> 6, lane = t & 63;
    int q = lane >> 4, l = lane & 15;
    int tile = blockIdx.x * 4 + wave;
    if (tile * 16 >= n) return;  // N % 16 == 0
    int node = tile * 16 + l;
    short8 afr[4][K / 32];
#pragma unroll
    for (int mb = 0; mb < 4; mb++)
#pragma unroll
        for (int s = 0; s < K / 32; s++)
            afr[mb][s] = *(const short8*)(wt + (mb * 16 + l) * K + s * 32 + q * 8);
    f32x4 acc[4] = {};
    const float* xr = X + (size_t)node * K + q * 8;
#pragma unroll
    for (int s = 0; s < K / 32; s++) {
        float4 xa = *(const float4*)(xr + s * 32);
        float4 xb = *(const float4*)(xr + s * 32 + 4);
        short8 bfr;
        bfr[0] = (short)f2bf(xa.x); bfr[1] = (short)f2bf(xa.y);
        bfr[2] = (short)f2bf(xa.z); bfr[3] = (short)f2bf(xa.w);
        bfr[4] = (short)f2bf(xb.x); bfr[5] = (short)f2bf(xb.y);
        bfr[6] = (short)f2bf(xb.z); bfr[7] = (short)f2bf(xb.w);
#pragma unroll
        for (int mb = 0; mb < 4; mb++)
            acc[mb] = __builtin_amdgcn_mfma_f32_16x16x32_bf16(afr[mb][s], bfr, acc[mb], 0, 0, 0);
    }
#pragma unroll
    for (int mb = 0; mb < 4; mb++) {
        ushort4 u;
        u.x = f2bf(acc[mb][0]); u.y = f2bf(acc[mb][1]);
        u.z = f2bf(acc[mb][2]); u.w = f2bf(acc[mb][3]);
        ushort4* slab = (ushort4*)H + (size_t)(mb >> 1) * (size_t)n * 8;
        slab[(size_t)node * 8 + (mb & 1) * 4 + q] = u;
    }
}

// bf16-input variant (layers 2,3; K=64): B-frags load directly, no casts
__global__ __launch_bounds__(256) void k_gemm_bf(const unsigned short* __restrict__ Xb,
                                                 const float* __restrict__ W,
                                                 unsigned short* __restrict__ H, int n) {
    const int K = 64;
    __shared__ short wt[64 * K];
    int t = threadIdx.x;
    for (int idx = t; idx < 64 * K; idx += 256) {
        int k = idx >> 6, ch = idx & 63;
        wt[ch * K + k] = (short)f2bf(W[idx]);
    }
    __syncthreads();
    int wave = t >> 6, lane = t & 63;
    int q = lane >> 4, l = lane & 15;
    int tile = blockIdx.x * 4 + wave;
    if (tile * 16 >= n) return;
    int node = tile * 16 + l;
    short8 afr[4][2];
#pragma unroll
    for (int mb = 0; mb < 4; mb++)
#pragma unroll
        for (int s = 0; s < 2; s++)
            afr[mb][s] = *(const short8*)(wt + (mb * 16 + l) * K + s * 32 + q * 8);
    f32x4 acc[4] = {};
    const short8* xr = (const short8*)(Xb + (size_t)node * 64);
#pragma unroll
    for (int s = 0; s < 2; s++) {
        short8 bfr = xr[s * 4 + q];
#pragma unroll
        for (int mb = 0; mb < 4; mb++)
            acc[mb] = __builtin_amdgcn_mfma_f32_16x16x32_bf16(afr[mb][s], bfr, acc[mb], 0, 0, 0);
    }
#pragma unroll
    for (int mb = 0; mb < 4; mb++) {
        ushort4 u;
        u.x = f2bf(acc[mb][0]); u.y = f2bf(acc[mb][1]);
        u.z = f2bf(acc[mb][2]); u.w = f2bf(acc[mb][3]);
        ushort4* slab = (ushort4*)H + (size_t)(mb >> 1) * (size_t)n * 8;
        slab[(size_t)node * 8 + (mb & 1) * 4 + q] = u;
    }
}

// Half-split aggregation: 64 nodes/block, 4 lanes x ushort8 (16B, 8ch) per node.
// One 64B line per edge per half. Layers 1,2 -> bf16 OutB; layer 3 -> fp32 S.
__global__ void k_agg(const unsigned short* __restrict__ H, const float2* __restrict__ col2,
                      const int* __restrict__ offs, const float* __restrict__ dis,
                      const float* __restrict__ bias,
                      const unsigned short* __restrict__ add1,
                      const unsigned short* __restrict__ add2,
                      unsigned short* __restrict__ OutB, float* __restrict__ OutS,
                      int n, int tiles) {
    int B = blockIdx.x;
    int xx = B & 7;
    int h = xx >> 2;                        // channel half (XCD heuristic)
    int within = (B >> 3) * 4 + (xx & 3);
    if (within >= tiles) return;
    int t = threadIdx.x;
    int node = within * 64 + (t >> 2);
    if (node >= n) return;
    int lane = t & 3;  // 8 channels each
    const short8* Hs = (const short8*)(H + (size_t)h * (size_t)n * 32);
    float dn = dis[node];
    float4 acc0, acc1;
    bh8f(Hs[(size_t)node * 4 + lane], acc0, acc1);
    acc0.x *= dn; acc0.y *= dn; acc0.z *= dn; acc0.w *= dn;
    acc1.x *= dn; acc1.y *= dn; acc1.z *= dn; acc1.w *= dn;
    int lo = offs[node], hi = offs[node + 1];
    int p = lo;
    for (; p + 4 <= hi; p += 4) {
        float2 e0 = col2[p], e1 = col2[p + 1], e2 = col2[p + 2], e3 = col2[p + 3];
        short8 g0 = Hs[(size_t)__float_as_int(e0.x) * 4 + lane];
        short8 g1 = Hs[(size_t)__float_as_int(e1.x) * 4 + lane];
        short8 g2 = Hs[(size_t)__float_as_int(e2.x) * 4 + lane];
        short8 g3 = Hs[(size_t)__float_as_int(e3.x) * 4 + lane];
        float4 a, b;
        bh8f(g0, a, b); acc0 = f4fma(e0.y, a, acc0); acc1 = f4fma(e0.y, b, acc1);
        bh8f(g1, a, b); acc0 = f4fma(e1.y, a, acc0); acc1 = f4fma(e1.y, b, acc1);
        bh8f(g2, a, b); acc0 = f4fma(e2.y, a, acc0); acc1 = f4fma(e2.y, b, acc1);
        bh8f(g3, a, b); acc0 = f4fma(e3.y, a, acc0); acc1 = f4fma(e3.y, b, acc1);
    }
    for (; p < hi; p++) {
        float2 e = col2[p];
        float4 a, b;
        bh8f(Hs[(size_t)__float_as_int(e.x) * 4 + lane], a, b);
        acc0 = f4fma(e.y, a, acc0);
        acc1 = f4fma(e.y, b, acc1);
    }
    const float4* bias4 = (const float4*)bias;
    float4 bb0 = bias4[h * 8 + lane * 2];
    float4 bb1 = bias4[h * 8 + lane * 2 + 1];
    float4 v0, v1;
    v0.x = fmaxf(acc0.x * dn + bb0.x, 0.f);
    v0.y = fmaxf(acc0.y * dn + bb0.y, 0.f);
    v0.z = fmaxf(acc0.z * dn + bb0.z, 0.f);
    v0.w = fmaxf(acc0.w * dn + bb0.w, 0.f);
    v1.x = fmaxf(acc1.x * dn + bb1.x, 0.f);
    v1.y = fmaxf(acc1.y * dn + bb1.y, 0.f);
    v1.z = fmaxf(acc1.z * dn + bb1.z, 0.f);
    v1.w = fmaxf(acc1.w * dn + bb1.w, 0.f);
    size_t slot = (size_t)node * 8 + h * 4 + lane;  // ushort8 row slot
    if (OutS) {
        float4 a10, a11, a20, a21;
        bh8f(((const short8*)add1)[slot], a10, a11);
        bh8f(((const short8*)add2)[slot], a20, a21);
        v0.x += a10.x + a20.x; v0.y += a10.y + a20.y;
        v0.z += a10.z + a20.z; v0.w += a10.w + a20.w;
        v1.x += a11.x + a21.x; v1.y += a11.y + a21.y;
        v1.z += a11.z + a21.z; v1.w += a11.w + a21.w;
        float4* S4 = (float4*)OutS;
        size_t oi = (size_t)node * 16 + (size_t)(h * 4 + lane) * 2;
        S4[oi] = v0;
        S4[oi + 1] = v1;
    } else {
        short8 o;
        o[0] = (short)f2bf(v0.x); o[1] = (short)f2bf(v0.y);
        o[2] = (short)f2bf(v0.z); o[3] = (short)f2bf(v0.w);
        o[4] = (short)f2bf(v1.x); o[5] = (short)f2bf(v1.y);
        o[6] = (short)f2bf(v1.z); o[7] = (short)f2bf(v1.w);
        ((short8*)OutB)[slot] = o;
    }
}

// one 64-thread block per graph: segment mean (sorted batch) + MLP head
__global__ void k_poolhead(const float* __restrict__ S, const int* __restrict__ batch,
                           const float* __restrict__ Wp1, const float* __restrict__ bp1,
                           const float* __restrict__ Wp2, const float* __restrict__ bp2,
                           float* __restrict__ out, int n, int G) {
    int g = blockIdx.x;
    int j = threadIdx.x;  // 0..63
    int a = 0, b = n;
    while (a < b) { int m = (a + b) >> 1; if (batch[m] < g) a = m + 1; else b = m; }
    int beg = a;
    b = n;
    while (a < b) { int m = (a + b) >> 1; if (batch[m] < g + 1) a = m + 1; else b = m; }
    int end = a;
    float sum = 0.f;
    int i = beg;
    for (; i + 2 <= end; i += 2)
        sum += S[(size_t)i * 64 + j] + S[(size_t)(i + 1) * 64 + j];
    if (i < end) sum += S[(size_t)i * 64 + j];
    float cnt = (float)(end - beg);
    float p = sum / fmaxf(cnt, 1.f);
    __shared__ float ps[64];
    __shared__ float ts[64];
    ps[j] = p;
    __syncthreads();
    float t1 = bp1[j];
#pragma unroll 8
    for (int k = 0; k < 64; k++) t1 += ps[k] * Wp1[k * 64 + j];
    t1 = fmaxf(t1, 0.f);
    ts[j] = t1;
    __syncthreads();
    if (j < 32) {
        float o = bp2[j];
#pragma unroll 8
        for (int k = 0; k < 64; k++) o += ts[k] * Wp2[k * 32 + j];
        out[(size_t)g * 32 + j] = o;
    }
}

extern "C" void kernel_launch(void* const* d_in, const int* in_sizes, int n_in,
                              void* d_out, int out_size, void* d_ws, size_t ws_size,
                              hipStream_t stream) {
    const float* x   = (const float*)d_in[0];
    const int*   ei  = (const int*)d_in[1];
    const int*   bat = (const int*)d_in[2];
    const float* W1  = (const float*)d_in[3];
    const float* b1  = (const float*)d_in[4];
    const float* W2  = (const float*)d_in[5];
    const float* b2  = (const float*)d_in[6];
    const float* W3  = (const float*)d_in[7];
    const float* b3  = (const float*)d_in[8];
    const float* Wp1 = (const float*)d_in[9];
    const float* bp1 = (const float*)d_in[10];
    const float* Wp2 = (const float*)d_in[11];
    const float* bp2 = (const float*)d_in[12];

    int N = in_sizes[0] / 128;
    int E = in_sizes[1] / 2;
    int G = out_size / 32;
    const int* src = ei;
    const int* dst = ei + E;

    char* w = (char*)d_ws;
    auto alloc = [&](size_t bytes) -> void* {
        void* p = (void*)w;
        w += (bytes + 255) & ~(size_t)255;
        return p;
    };
    int NB = (N + 255) / 256;  // buckets (<=256)
    int*            offs    = (int*)alloc((size_t)(N + 1) * 4);
    float2*         col2    = (float2*)alloc((size_t)E * 8);
    float*          dis     = (float*)alloc((size_t)N * 4);
    int*            hist    = (int*)alloc((size_t)256 * 256 * 4);
    int*            cursorA = (int*)alloc((size_t)256 * 256 * 4);
    int*            tot     = (int*)alloc((size_t)256 * 4);
    unsigned*       ebuf    = (unsigned*)alloc((size_t)E * 4);
    unsigned short* Hb      = (unsigned short*)alloc((size_t)N * 64 * 2);
    unsigned short* X1      = (unsigned short*)alloc((size_t)N * 64 * 2);
    unsigned short* X2      = (unsigned short*)alloc((size_t)N * 64 * 2);
    float*          S       = (float*)alloc((size_t)N * 64 * 4);

    int chunk = (E + 255) / 256;

    kA_hist<<<256, 256, 0, stream>>>(dst, hist, E, chunk);
    kA_colscan<<<256, 256, 0, stream>>>(hist, cursorA, tot);
    kA_scatter<<<256, 256, 0, stream>>>(src, dst, cursorA, tot, ebuf, E, chunk);
    kB1<<<NB, 256, 0, stream>>>(ebuf, tot, dis, offs, N, E);
    kB2<<<NB, 256, 0, stream>>>(ebuf, tot, dis, offs, col2, N, E);

    int ggemm = ((N >> 4) + 3) / 4;       // 4 waves/block, 16 nodes/wave
    int tiles = (N + 63) / 64;            // agg tiles (64 nodes)
    int gagg  = ((tiles + 3) / 4) * 8;    // both halves covered
    k_gemm_f32<128><<<ggemm, 256, 0, stream>>>(x, W1, Hb, N);
    k_agg<<<gagg, 256, 0, stream>>>(Hb, col2, offs, dis, b1, nullptr, nullptr, X1, nullptr, N, tiles);
    k_gemm_bf<<<ggemm, 256, 0, stream>>>(X1, W2, Hb, N);
    k_agg<<<gagg, 256, 0, stream>>>(Hb, col2, offs, dis, b2, nullptr, nullptr, X2, nullptr, N, tiles);
    k_gemm_bf<<<ggemm, 256, 0, stream>>>(X2, W3, Hb, N);
    k_agg<<<gagg, 256, 0, stream>>>(Hb, col2, offs, dis, b3, X1, X2, nullptr, S, N, tiles);

    k_poolhead<<<G, 64, 0, stream>>>(S, bat, Wp1, bp1, Wp2, bp2, (float*)d_out, N, G);
}

// Round 10
// 236.982 us; speedup vs baseline: 3.0494x; 1.0340x over previous
//
#include <hip/hip_runtime.h>
#include <math.h>

// ---------------------------------------------------------------------------
// GNNEncoder: 3x GCNConv(relu) -> sum of layers -> global_mean_pool -> MLP
// CSR via bucketed counting sort (no global atomics). H/X1/X2 bf16 node-major
// (128B rows). Single-pass agg: 8 lanes x ushort8 per node, packed 4B col
// entries (fp16 dis | 16-bit src). Gemms on MFMA 16x16x32 bf16.
// ---------------------------------------------------------------------------

typedef short short8 __attribute__((ext_vector_type(8)));
typedef float f32x4 __attribute__((ext_vector_type(4)));

__device__ inline float bf2f(unsigned short h) {
    return __uint_as_float((unsigned)h << 16);
}
__device__ inline unsigned short f2bf(float f) {  // round-to-nearest-even
    unsigned u = __float_as_uint(f);
    return (unsigned short)((u + (0x7FFFu + ((u >> 16) & 1u))) >> 16);
}
__device__ inline unsigned short f2h(float f) {
    union { _Float16 h; unsigned short u; } c;
    c.h = (_Float16)f;
    return c.u;
}
__device__ inline float h2f(unsigned short u) {
    union { unsigned short u; _Float16 h; } c;
    c.u = u;
    return (float)c.h;
}
__device__ inline void bh8f(short8 u, float4& a, float4& b) {
    a.x = bf2f((unsigned short)u[0]); a.y = bf2f((unsigned short)u[1]);
    a.z = bf2f((unsigned short)u[2]); a.w = bf2f((unsigned short)u[3]);
    b.x = bf2f((unsigned short)u[4]); b.y = bf2f((unsigned short)u[5]);
    b.z = bf2f((unsigned short)u[6]); b.w = bf2f((unsigned short)u[7]);
}
__device__ inline float4 f4fma(float s, float4 a, float4 acc) {
    acc.x += s * a.x; acc.y += s * a.y; acc.z += s * a.z; acc.w += s * a.w;
    return acc;
}

// ---- pass A: coarse bucket hist of dst>>8 (LDS only) ----------------------
__global__ void kA_hist(const int* __restrict__ dst, int* __restrict__ hist,
                        int E, int chunk) {
    __shared__ int h[256];
    int t = threadIdx.x;
    h[t] = 0;
    __syncthreads();
    int e0 = blockIdx.x * chunk;
    int e1 = min(e0 + chunk, E);
    for (int e = e0 + t; e < e1; e += 256) atomicAdd(&h[dst[e] >> 8], 1);
    __syncthreads();
    hist[blockIdx.x * 256 + t] = h[t];
}

// block k scans column k of hist over chunk-blocks -> cursorA, tot
__global__ void kA_colscan(const int* __restrict__ hist, int* __restrict__ cursorA,
                           int* __restrict__ tot) {
    __shared__ int s[256];
    int t = threadIdx.x;
    int k = blockIdx.x;
    int v = hist[t * 256 + k];
    s[t] = v;
    __syncthreads();
    for (int st = 1; st < 256; st <<= 1) {
        int u = s[t];
        if (t >= st) u += s[t - st];
        __syncthreads();
        s[t] = u;
        __syncthreads();
    }
    cursorA[t * 256 + k] = s[t] - v;
    if (t == 255) tot[k] = s[255];
}

// scatter packed (dstLow<<24 | src) into bucket-contiguous ebuf
__global__ void kA_scatter(const int* __restrict__ src, const int* __restrict__ dst,
                           const int* __restrict__ cursorA, const int* __restrict__ tot,
                           unsigned* __restrict__ ebuf, int E, int chunk) {
    __shared__ int s[256];
    __shared__ int cur[256];
    int t = threadIdx.x;
    s[t] = tot[t];
    __syncthreads();
    for (int st = 1; st < 256; st <<= 1) {
        int u = s[t];
        if (t >= st) u += s[t - st];
        __syncthreads();
        s[t] = u;
        __syncthreads();
    }
    int bstart = (t == 0) ? 0 : s[t - 1];
    cur[t] = cursorA[blockIdx.x * 256 + t] + bstart;
    __syncthreads();
    int e0 = blockIdx.x * chunk;
    int e1 = min(e0 + chunk, E);
    for (int e = e0 + t; e < e1; e += 256) {
        int d = dst[e];
        int p = atomicAdd(&cur[d >> 8], 1);
        ebuf[p] = ((unsigned)(d & 255) << 24) | (unsigned)src[e];
    }
}

// kB1: per-bucket exact degree (LDS hist) -> dis, offs
__global__ void kB1(const unsigned* __restrict__ ebuf, const int* __restrict__ tot,
                    float* __restrict__ dis, int* __restrict__ offs, int N, int E) {
    __shared__ int s[256];
    __shared__ int h[256];
    int t = threadIdx.x;
    int k = blockIdx.x;
    s[t] = tot[t];
    __syncthreads();
    for (int st = 1; st < 256; st <<= 1) {
        int u = s[t];
        if (t >= st) u += s[t - st];
        __syncthreads();
        s[t] = u;
        __syncthreads();
    }
    int lo = (k == 0) ? 0 : s[k - 1];
    int hi = s[k];
    h[t] = 0;
    __syncthreads();
    for (int p = lo + t; p < hi; p += 256) atomicAdd(&h[ebuf[p] >> 24], 1);
    __syncthreads();
    int c = h[t];
    int node = k * 256 + t;
    if (node < N) dis[node] = rsqrtf((float)(c + 1));  // +1 self-loop
    s[t] = c;
    __syncthreads();
    for (int st = 1; st < 256; st <<= 1) {
        int u = s[t];
        if (t >= st) u += s[t - st];
        __syncthreads();
        s[t] = u;
        __syncthreads();
    }
    if (node < N) offs[node] = lo + s[t] - c;
    if (node == N - 1) offs[N] = E;
}

// kB2: scatter packed col = (fp16(dis[src])<<16 | src) into CSR windows
// (requires N <= 65536; here N = 50000)
__global__ void kB2(const unsigned* __restrict__ ebuf, const int* __restrict__ tot,
                    const float* __restrict__ dis, const int* __restrict__ offs,
                    unsigned* __restrict__ col, int N, int E) {
    __shared__ int s[256];
    __shared__ int cur[256];
    int t = threadIdx.x;
    int k = blockIdx.x;
    s[t] = tot[t];
    __syncthreads();
    for (int st = 1; st < 256; st <<= 1) {
        int u = s[t];
        if (t >= st) u += s[t - st];
        __syncthreads();
        s[t] = u;
        __syncthreads();
    }
    int lo = (k == 0) ? 0 : s[k - 1];
    int hi = s[k];
    int node = k * 256 + t;
    cur[t] = (node < N) ? offs[node] : 0;
    __syncthreads();
    for (int p = lo + t; p < hi; p += 256) {
        unsigned e = ebuf[p];
        int srcI = (int)(e & 0x00FFFFFFu);
        int q = atomicAdd(&cur[e >> 24], 1);
        col[q] = ((unsigned)f2h(dis[srcI]) << 16) | (unsigned)srcI;
    }
}

// ---- MFMA dense transforms: D[ch][node] = sum_k W[k][ch] * X[node][k] -----
// A = W^T bf16 (LDS), B = X rows bf16. C layout col=node, row=ch.
// H row layout: node-major, 64 ch contiguous (128B).

// fp32-input variant (layer 1, K=128)
template <int K>
__global__ __launch_bounds__(256) void k_gemm_f32(const float* __restrict__ X,
                                                  const float* __restrict__ W,
                                                  unsigned short* __restrict__ H, int n) {
    __shared__ short wt[64 * K];
    int t = threadIdx.x;
    for (int idx = t; idx < 64 * K; idx += 256) {
        int k = idx >> 6, ch = idx & 63;
        wt[ch * K + k] = (short)f2bf(W[idx]);
    }
    __syncthreads();
    int wave = t >> 6, lane = t & 63;
    int q = lane >> 4, l = lane & 15;
    int tile = blockIdx.x * 4 + wave;
    if (tile * 16 >= n) return;  // N % 16 == 0
    int node = tile * 16 + l;
    short8 afr[4][K / 32];
#pragma unroll
    for (int mb = 0; mb < 4; mb++)
#pragma unroll
        for (int s = 0; s < K / 32; s++)
            afr[mb][s] = *(const short8*)(wt + (mb * 16 + l) * K + s * 32 + q * 8);
    f32x4 acc[4] = {};
    const float* xr = X + (size_t)node * K + q * 8;
#pragma unroll
    for (int s = 0; s < K / 32; s++) {
        float4 xa = *(const float4*)(xr + s * 32);
        float4 xb = *(const float4*)(xr + s * 32 + 4);
        short8 bfr;
        bfr[0] = (short)f2bf(xa.x); bfr[1] = (short)f2bf(xa.y);
        bfr[2] = (short)f2bf(xa.z); bfr[3] = (short)f2bf(xa.w);
        bfr[4] = (short)f2bf(xb.x); bfr[5] = (short)f2bf(xb.y);
        bfr[6] = (short)f2bf(xb.z); bfr[7] = (short)f2bf(xb.w);
#pragma unroll
        for (int mb = 0; mb < 4; mb++)
            acc[mb] = __builtin_amdgcn_mfma_f32_16x16x32_bf16(afr[mb][s], bfr, acc[mb], 0, 0, 0);
    }
#pragma unroll
    for (int mb = 0; mb < 4; mb++) {
        ushort4 u;
        u.x = f2bf(acc[mb][0]); u.y = f2bf(acc[mb][1]);
        u.z = f2bf(acc[mb][2]); u.w = f2bf(acc[mb][3]);
        ((ushort4*)H)[(size_t)node * 16 + mb * 4 + q] = u;  // ch = mb*16+q*4
    }
}

// bf16-input variant (layers 2,3; K=64)
__global__ __launch_bounds__(256) void k_gemm_bf(const unsigned short* __restrict__ Xb,
                                                 const float* __restrict__ W,
                                                 unsigned short* __restrict__ H, int n) {
    const int K = 64;
    __shared__ short wt[64 * K];
    int t = threadIdx.x;
    for (int idx = t; idx < 64 * K; idx += 256) {
        int k = idx >> 6, ch = idx & 63;
        wt[ch * K + k] = (short)f2bf(W[idx]);
    }
    __syncthreads();
    int wave = t >> 6, lane = t & 63;
    int q = lane >> 4, l = lane & 15;
    int tile = blockIdx.x * 4 + wave;
    if (tile * 16 >= n) return;
    int node = tile * 16 + l;
    short8 afr[4][2];
#pragma unroll
    for (int mb = 0; mb < 4; mb++)
#pragma unroll
        for (int s = 0; s < 2; s++)
            afr[mb][s] = *(const short8*)(wt + (mb * 16 + l) * K + s * 32 + q * 8);
    f32x4 acc[4] = {};
    const short8* xr = (const short8*)(Xb + (size_t)node * 64);
#pragma unroll
    for (int s = 0; s < 2; s++) {
        short8 bfr = xr[s * 4 + q];
#pragma unroll
        for (int mb = 0; mb < 4; mb++)
            acc[mb] = __builtin_amdgcn_mfma_f32_16x16x32_bf16(afr[mb][s], bfr, acc[mb], 0, 0, 0);
    }
#pragma unroll
    for (int mb = 0; mb < 4; mb++) {
        ushort4 u;
        u.x = f2bf(acc[mb][0]); u.y = f2bf(acc[mb][1]);
        u.z = f2bf(acc[mb][2]); u.w = f2bf(acc[mb][3]);
        ((ushort4*)H)[(size_t)node * 16 + mb * 4 + q] = u;
    }
}

// Single-pass aggregation: 32 nodes/block, 8 lanes x ushort8 (16B, 8ch) per
// node. Per edge: one packed col word (broadcast) + full-row gather (2 lines).
__global__ void k_agg(const unsigned short* __restrict__ H, const unsigned* __restrict__ col,
                      const int* __restrict__ offs, const float* __restrict__ dis,
                      const float* __restrict__ bias,
                      const unsigned short* __restrict__ add1,
                      const unsigned short* __restrict__ add2,
                      unsigned short* __restrict__ OutB, float* __restrict__ OutS, int n) {
    int t = threadIdx.x;
    int node = blockIdx.x * 32 + (t >> 3);
    if (node >= n) return;
    int lane = t & 7;  // 8 channels each
    const short8* Hs = (const short8*)H;
    float dn = dis[node];
    float4 acc0, acc1;
    bh8f(Hs[(size_t)node * 8 + lane], acc0, acc1);
    acc0.x *= dn; acc0.y *= dn; acc0.z *= dn; acc0.w *= dn;
    acc1.x *= dn; acc1.y *= dn; acc1.z *= dn; acc1.w *= dn;
    int lo = offs[node], hi = offs[node + 1];
    int p = lo;
    for (; p + 4 <= hi; p += 4) {
        unsigned e0 = col[p], e1 = col[p + 1], e2 = col[p + 2], e3 = col[p + 3];
        short8 g0 = Hs[(size_t)(e0 & 0xFFFFu) * 8 + lane];
        short8 g1 = Hs[(size_t)(e1 & 0xFFFFu) * 8 + lane];
        short8 g2 = Hs[(size_t)(e2 & 0xFFFFu) * 8 + lane];
        short8 g3 = Hs[(size_t)(e3 & 0xFFFFu) * 8 + lane];
        float w0 = h2f((unsigned short)(e0 >> 16));
        float w1 = h2f((unsigned short)(e1 >> 16));
        float w2 = h2f((unsigned short)(e2 >> 16));
        float w3 = h2f((unsigned short)(e3 >> 16));
        float4 a, b;
        bh8f(g0, a, b); acc0 = f4fma(w0, a, acc0); acc1 = f4fma(w0, b, acc1);
        bh8f(g1, a, b); acc0 = f4fma(w1, a, acc0); acc1 = f4fma(w1, b, acc1);
        bh8f(g2, a, b); acc0 = f4fma(w2, a, acc0); acc1 = f4fma(w2, b, acc1);
        bh8f(g3, a, b); acc0 = f4fma(w3, a, acc0); acc1 = f4fma(w3, b, acc1);
    }
    for (; p < hi; p++) {
        unsigned e = col[p];
        float w = h2f((unsigned short)(e >> 16));
        float4 a, b;
        bh8f(Hs[(size_t)(e & 0xFFFFu) * 8 + lane], a, b);
        acc0 = f4fma(w, a, acc0);
        acc1 = f4fma(w, b, acc1);
    }
    const float4* bias4 = (const float4*)bias;
    float4 bb0 = bias4[lane * 2];
    float4 bb1 = bias4[lane * 2 + 1];
    float4 v0, v1;
    v0.x = fmaxf(acc0.x * dn + bb0.x, 0.f);
    v0.y = fmaxf(acc0.y * dn + bb0.y, 0.f);
    v0.z = fmaxf(acc0.z * dn + bb0.z, 0.f);
    v0.w = fmaxf(acc0.w * dn + bb0.w, 0.f);
    v1.x = fmaxf(acc1.x * dn + bb1.x, 0.f);
    v1.y = fmaxf(acc1.y * dn + bb1.y, 0.f);
    v1.z = fmaxf(acc1.z * dn + bb1.z, 0.f);
    v1.w = fmaxf(acc1.w * dn + bb1.w, 0.f);
    size_t slot = (size_t)node * 8 + lane;  // ushort8 slot
    if (OutS) {
        float4 a10, a11, a20, a21;
        bh8f(((const short8*)add1)[slot], a10, a11);
        bh8f(((const short8*)add2)[slot], a20, a21);
        v0.x += a10.x + a20.x; v0.y += a10.y + a20.y;
        v0.z += a10.z + a20.z; v0.w += a10.w + a20.w;
        v1.x += a11.x + a21.x; v1.y += a11.y + a21.y;
        v1.z += a11.z + a21.z; v1.w += a11.w + a21.w;
        float4* S4 = (float4*)OutS;
        size_t oi = (size_t)node * 16 + (size_t)lane * 2;
        S4[oi] = v0;
        S4[oi + 1] = v1;
    } else {
        short8 o;
        o[0] = (short)f2bf(v0.x); o[1] = (short)f2bf(v0.y);
        o[2] = (short)f2bf(v0.z); o[3] = (short)f2bf(v0.w);
        o[4] = (short)f2bf(v1.x); o[5] = (short)f2bf(v1.y);
        o[6] = (short)f2bf(v1.z); o[7] = (short)f2bf(v1.w);
        ((short8*)OutB)[slot] = o;
    }
}

// one 64-thread block per graph: segment mean (sorted batch) + MLP head
__global__ void k_poolhead(const float* __restrict__ S, const int* __restrict__ batch,
                           const float* __restrict__ Wp1, const float* __restrict__ bp1,
                           const float* __restrict__ Wp2, const float* __restrict__ bp2,
                           float* __restrict__ out, int n, int G) {
    int g = blockIdx.x;
    int j = threadIdx.x;  // 0..63
    int a = 0, b = n;
    while (a < b) { int m = (a + b) >> 1; if (batch[m] < g) a = m + 1; else b = m; }
    int beg = a;
    b = n;
    while (a < b) { int m = (a + b) >> 1; if (batch[m] < g + 1) a = m + 1; else b = m; }
    int end = a;
    float sum = 0.f;
    int i = beg;
    for (; i + 2 <= end; i += 2)
        sum += S[(size_t)i * 64 + j] + S[(size_t)(i + 1) * 64 + j];
    if (i < end) sum += S[(size_t)i * 64 + j];
    float cnt = (float)(end - beg);
    float p = sum / fmaxf(cnt, 1.f);
    __shared__ float ps[64];
    __shared__ float ts[64];
    ps[j] = p;
    __syncthreads();
    float t1 = bp1[j];
#pragma unroll 8
    for (int k = 0; k < 64; k++) t1 += ps[k] * Wp1[k * 64 + j];
    t1 = fmaxf(t1, 0.f);
    ts[j] = t1;
    __syncthreads();
    if (j < 32) {
        float o = bp2[j];
#pragma unroll 8
        for (int k = 0; k < 64; k++) o += ts[k] * Wp2[k * 32 + j];
        out[(size_t)g * 32 + j] = o;
    }
}

extern "C" void kernel_launch(void* const* d_in, const int* in_sizes, int n_in,
                              void* d_out, int out_size, void* d_ws, size_t ws_size,
                              hipStream_t stream) {
    const float* x   = (const float*)d_in[0];
    const int*   ei  = (const int*)d_in[1];
    const int*   bat = (const int*)d_in[2];
    const float* W1  = (const float*)d_in[3];
    const float* b1  = (const float*)d_in[4];
    const float* W2  = (const float*)d_in[5];
    const float* b2  = (const float*)d_in[6];
    const float* W3  = (const float*)d_in[7];
    const float* b3  = (const float*)d_in[8];
    const float* Wp1 = (const float*)d_in[9];
    const float* bp1 = (const float*)d_in[10];
    const float* Wp2 = (const float*)d_in[11];
    const float* bp2 = (const float*)d_in[12];

    int N = in_sizes[0] / 128;
    int E = in_sizes[1] / 2;
    int G = out_size / 32;
    const int* src = ei;
    const int* dst = ei + E;

    char* w = (char*)d_ws;
    auto alloc = [&](size_t bytes) -> void* {
        void* p = (void*)w;
        w += (bytes + 255) & ~(size_t)255;
        return p;
    };
    int NB = (N + 255) / 256;  // buckets (<=256)
    int*            offs    = (int*)alloc((size_t)(N + 1) * 4);
    unsigned*       col     = (unsigned*)alloc((size_t)E * 4);
    float*          dis     = (float*)alloc((size_t)N * 4);
    int*            hist    = (int*)alloc((size_t)256 * 256 * 4);
    int*            cursorA = (int*)alloc((size_t)256 * 256 * 4);
    int*            tot     = (int*)alloc((size_t)256 * 4);
    unsigned*       ebuf    = (unsigned*)alloc((size_t)E * 4);
    unsigned short* Hb      = (unsigned short*)alloc((size_t)N * 64 * 2);
    unsigned short* X1      = (unsigned short*)alloc((size_t)N * 64 * 2);
    unsigned short* X2      = (unsigned short*)alloc((size_t)N * 64 * 2);
    float*          S       = (float*)alloc((size_t)N * 64 * 4);

    int chunk = (E + 255) / 256;

    kA_hist<<<256, 256, 0, stream>>>(dst, hist, E, chunk);
    kA_colscan<<<256, 256, 0, stream>>>(hist, cursorA, tot);
    kA_scatter<<<256, 256, 0, stream>>>(src, dst, cursorA, tot, ebuf, E, chunk);
    kB1<<<NB, 256, 0, stream>>>(ebuf, tot, dis, offs, N, E);
    kB2<<<NB, 256, 0, stream>>>(ebuf, tot, dis, offs, col, N, E);

    int ggemm = ((N >> 4) + 3) / 4;  // 4 waves/block, 16 nodes/wave
    int gagg  = (N + 31) / 32;       // 32 nodes/block
    k_gemm_f32<128><<<ggemm, 256, 0, stream>>>(x, W1, Hb, N);
    k_agg<<<gagg, 256, 0, stream>>>(Hb, col, offs, dis, b1, nullptr, nullptr, X1, nullptr, N);
    k_gemm_bf<<<ggemm, 256, 0, stream>>>(X1, W2, Hb, N);
    k_agg<<<gagg, 256, 0, stream>>>(Hb, col, offs, dis, b2, nullptr, nullptr, X2, nullptr, N);
    k_gemm_bf<<<ggemm, 256, 0, stream>>>(X2, W3, Hb, N);
    k_agg<<<gagg, 256, 0, stream>>>(Hb, col, offs, dis, b3, X1, X2, nullptr, S, N);

    k_poolhead<<<G, 64, 0, stream>>>(S, bat, Wp1, bp1, Wp2, bp2, (float*)d_out, N, G);
}